// Round 5
// baseline (118.998 us; speedup 1.0000x reference)
//
#include <hip/hip_runtime.h>

typedef float f32x4 __attribute__((ext_vector_type(4)));
typedef __bf16 bf16x8 __attribute__((ext_vector_type(8)));

__device__ __forceinline__ unsigned short f2bf(float f) {
  unsigned u = __builtin_bit_cast(unsigned, f);
  u = (u + 0x7FFFu + ((u >> 16) & 1u)) >> 16;
  return (unsigned short)u;
}

__device__ __forceinline__ f32x4 MFMA16(uint4 a, uint4 b, f32x4 c) {
  return __builtin_amdgcn_mfma_f32_16x16x32_bf16(
      __builtin_bit_cast(bf16x8, a), __builtin_bit_cast(bf16x8, b), c, 0, 0, 0);
}

__device__ __forceinline__ void barrier_lgkm_only() {
  // wait own ds_writes only; do NOT drain vmcnt (prefetch stays in flight)
  asm volatile("s_waitcnt lgkmcnt(0)" ::: "memory");
  __builtin_amdgcn_s_barrier();
  asm volatile("" ::: "memory");
}

// ---------------- weight prep: pack bf16, padded images into ws ----------
// wd image:  [8 chunks][128 rows(o)][40 cols(32 valid + 8 pad)] = 40960 elems
// wrs image: [3 passes][128 rows][136 cols(128 valid + 8 pad)]  = 52224 elems
__global__ void wn_prep(const float* __restrict__ wd, const float* __restrict__ wres,
                        const float* __restrict__ wskip, unsigned short* __restrict__ ws16) {
  int g = blockIdx.x * 256 + threadIdx.x;
  if (g < 40960) {
    int kc = g / 5120, rem = g - kc * 5120;
    int o = rem / 40, c = rem - o * 40;
    float v = 0.f;
    if (c < 32) {
      int k = kc * 32 + c;
      int tap = k >> 7, i = k & 127;
      v = wd[(o << 8) + (i << 1) + tap];   // w_dil[o][i][tap], shape (128,128,2)
    }
    ws16[g] = f2bf(v);
  } else {
    int g2 = g - 40960;  // < 52224 (grid sized exactly)
    int p = g2 / 17408, rem = g2 - p * 17408;
    int r = rem / 136, c = rem - r * 136;
    float v = 0.f;
    if (c < 128) {
      if (p == 0) v = wres[(r << 7) + c];
      else        v = wskip[(((p - 1) << 7) + r) * 128 + c];
    }
    ws16[40960 + g2] = f2bf(v);
  }
}

// ---------------- fused main kernel ----------------
// LDS: xls[2][128][40] (20480 B), actT[128][136] (34816 B) ALIASES xls —
// safe: final stage-1 barrier orders all xls reads before actT writes.
// LDS block = 34816 B; __launch_bounds__(512,4) -> 2 blocks/CU.
__global__ __launch_bounds__(512, 4) void wn_main(
    const float* __restrict__ x,
    const float* __restrict__ bres_g,
    const float* __restrict__ bskip_g,
    const unsigned short* __restrict__ wd_img,
    const unsigned short* __restrict__ wrs_img,
    float* __restrict__ out,
    float* __restrict__ skipo) {
  extern __shared__ unsigned short lds[];
  unsigned short* xls  = lds;   // [2][128][40]
  unsigned short* actT = lds;   // [128][136], aliases xls (sequenced)

  const int tile = blockIdx.x;
  const int b = blockIdx.y;
  const int t0 = tile * 128;
  const int tid = threadIdx.x;
  const int lane = tid & 63;
  const int wv = tid >> 6;
  const int mw = wv >> 2;     // 0..1 -> M offset mw*64
  const int nw = wv & 3;      // 0..3 -> N offset nw*32
  const int l15 = lane & 15;
  const int lhi = lane >> 4;

  // staging mapping: k-major lanes (conflict-floor b64 writes)
  const int kq = tid & 7;     // k-group of 4
  const int tpr = tid >> 3;   // 0..63 -> t pair

  const float* xb_base = x + (size_t)b * (128 * 16384);

  // x prefetch ring, depth 2 (16 VGPRs)
  float2 xr[2][4];

  auto issueX = [&](int c) {
    int s = c & 1;
    int kglob = c * 32 + kq * 4;
    int tap = kglob >> 7;
    int ib = kglob & 127;
    const float* p = xb_base + (size_t)ib * 16384 + (t0 + tap * 512 + tpr * 2);
    xr[s][0] = *(const float2*)(p);
    xr[s][1] = *(const float2*)(p + 16384);
    xr[s][2] = *(const float2*)(p + 32768);
    xr[s][3] = *(const float2*)(p + 49152);
  };
  auto writeX = [&](int c, int buf) {  // waits chunk c's regs (counted vmcnt)
    int s = c & 1;
    unsigned short* dst = xls + buf * 5120;
    int r0 = tpr * 2;
    ushort4 a0, a1;
    a0.x = f2bf(xr[s][0].x); a0.y = f2bf(xr[s][1].x); a0.z = f2bf(xr[s][2].x); a0.w = f2bf(xr[s][3].x);
    a1.x = f2bf(xr[s][0].y); a1.y = f2bf(xr[s][1].y); a1.z = f2bf(xr[s][2].y); a1.w = f2bf(xr[s][3].y);
    *(ushort4*)(dst + r0 * 40 + kq * 4) = a0;
    *(ushort4*)(dst + (r0 + 1) * 40 + kq * 4) = a1;
  };

  f32x4 acc[4][2];
#pragma unroll
  for (int i = 0; i < 4; ++i)
#pragma unroll
    for (int j = 0; j < 2; ++j) acc[i][j] = (f32x4){0.f, 0.f, 0.f, 0.f};

  // ---- stage 1: pre = [W0|W1] @ [x(t); x(t+512)], K=256 in 8 chunks ----
  issueX(0); issueX(1);
  writeX(0, 0);               // counted wait: chunk 1 stays in flight
  barrier_lgkm_only();

#pragma unroll
  for (int kc = 0; kc < 8; ++kc) {
    const int buf = kc & 1;
    // A-frags from L2-hot global image, issued first
    uint4 af[4];
#pragma unroll
    for (int mi = 0; mi < 4; ++mi)
      af[mi] = *(const uint4*)(wd_img + kc * 5120 + (mw * 64 + mi * 16 + l15) * 40 + lhi * 8);
    if (kc + 2 < 8) issueX(kc + 2);   // depth-2 prefetch
    uint4 bfr[2];
    const unsigned short* xb = xls + buf * 5120;
#pragma unroll
    for (int ni = 0; ni < 2; ++ni)
      bfr[ni] = *(const uint4*)(xb + (nw * 32 + ni * 16 + l15) * 40 + lhi * 8);
#pragma unroll
    for (int mi = 0; mi < 4; ++mi)
#pragma unroll
      for (int ni = 0; ni < 2; ++ni)
        acc[mi][ni] = MFMA16(af[mi], bfr[ni], acc[mi][ni]);
    if (kc < 7) writeX(kc + 1, buf ^ 1);  // loads landed ~1 full iter ago
    barrier_lgkm_only();
  }

  // ---- activation -> actT[t][o] (aliases xls; ordered by final barrier) ----
#pragma unroll
  for (int mi = 0; mi < 4; ++mi) {
#pragma unroll
    for (int ni = 0; ni < 2; ++ni) {
      ushort4 av;
#pragma unroll
      for (int r = 0; r < 4; ++r) {
        float p = acc[mi][ni][r];
        p = fminf(fmaxf(p, -15.f), 15.f);
        float ep = __expf(p);
        float e2 = ep * ep;
        float sg = ep * __builtin_amdgcn_rcpf(1.f + ep);
        float th = (e2 - 1.f) * __builtin_amdgcn_rcpf(e2 + 1.f);
        ((unsigned short*)&av)[r] = f2bf(th * sg);
      }
      int trow = nw * 32 + ni * 16 + l15;
      int o0 = mw * 64 + mi * 16 + lhi * 4;
      *(ushort4*)(actT + trow * 136 + o0) = av;
    }
  }
  __syncthreads();   // single full barrier: actT handoff

  // ---- stage 2: out (pass 0) and skip (passes 1,2); barrier-free ----
  const int npass = (tile >= 92) ? 3 : 1;
  for (int p = 0; p < npass; ++p) {
    f32x4 acc2[4][2];
#pragma unroll
    for (int i = 0; i < 4; ++i)
#pragma unroll
      for (int j = 0; j < 2; ++j) acc2[i][j] = (f32x4){0.f, 0.f, 0.f, 0.f};

#pragma unroll
    for (int kk = 0; kk < 4; ++kk) {
      uint4 af[4], bfr[2];
#pragma unroll
      for (int mi = 0; mi < 4; ++mi)
        af[mi] = *(const uint4*)(wrs_img + p * 17408 + (mw * 64 + mi * 16 + l15) * 136 + kk * 32 + lhi * 8);
#pragma unroll
      for (int ni = 0; ni < 2; ++ni)
        bfr[ni] = *(const uint4*)(actT + (nw * 32 + ni * 16 + l15) * 136 + kk * 32 + lhi * 8);
#pragma unroll
      for (int mi = 0; mi < 4; ++mi)
#pragma unroll
        for (int ni = 0; ni < 2; ++ni)
          acc2[mi][ni] = MFMA16(af[mi], bfr[ni], acc2[mi][ni]);
    }

    if (p == 0) {
#pragma unroll
      for (int mi = 0; mi < 4; ++mi) {
        int o0 = mw * 64 + mi * 16 + lhi * 4;
        float br[4];
#pragma unroll
        for (int r = 0; r < 4; ++r) br[r] = bres_g[o0 + r];
#pragma unroll
        for (int ni = 0; ni < 2; ++ni) {
          int tl = nw * 32 + ni * 16 + l15;
#pragma unroll
          for (int r = 0; r < 4; ++r) {
            size_t row = (size_t)(b * 128 + o0 + r);
            float v = acc2[mi][ni][r] + br[r] + x[row * 16384 + 512 + t0 + tl];
            out[row * 15872 + t0 + tl] = v;
          }
        }
      }
    } else {
#pragma unroll
      for (int mi = 0; mi < 4; ++mi) {
        int o2 = (p - 1) * 128 + mw * 64 + mi * 16 + lhi * 4;
        float bs[4];
#pragma unroll
        for (int r = 0; r < 4; ++r) bs[r] = bskip_g[o2 + r];
#pragma unroll
        for (int ni = 0; ni < 2; ++ni) {
          int tl = nw * 32 + ni * 16 + l15;
          int s = t0 + tl - 11776;
#pragma unroll
          for (int r = 0; r < 4; ++r) {
            skipo[(size_t)(b * 256 + o2 + r) * 4096 + s] = acc2[mi][ni][r] + bs[r];
          }
        }
      }
    }
  }
}

extern "C" void kernel_launch(void* const* d_in, const int* in_sizes, int n_in,
                              void* d_out, int out_size, void* d_ws, size_t ws_size,
                              hipStream_t stream) {
  const float* x      = (const float*)d_in[0];
  const float* w_dil  = (const float*)d_in[1];
  const float* w_res  = (const float*)d_in[2];
  const float* b_res  = (const float*)d_in[3];
  const float* w_skip = (const float*)d_in[4];
  const float* b_skip = (const float*)d_in[5];
  unsigned short* ws16 = (unsigned short*)d_ws;
  float* out = (float*)d_out;
  float* skipo = out + 16252928;  // 8*128*15872

  wn_prep<<<364, 256, 0, stream>>>(w_dil, w_res, w_skip, ws16);

  dim3 grid(124, 8);
  wn_main<<<grid, 512, 34816, stream>>>(x, b_res, b_skip, ws16, ws16 + 40960, out, skipo);
}

// Round 6
// 81.935 us; speedup vs baseline: 1.4523x; 1.4523x over previous
//
#include <hip/hip_runtime.h>

typedef float f32x4 __attribute__((ext_vector_type(4)));
typedef __bf16 bf16x8 __attribute__((ext_vector_type(8)));

__device__ __forceinline__ unsigned short f2bf(float f) {
  unsigned u = __builtin_bit_cast(unsigned, f);
  u = (u + 0x7FFFu + ((u >> 16) & 1u)) >> 16;
  return (unsigned short)u;
}

__device__ __forceinline__ f32x4 MFMA16(uint4 a, uint4 b, f32x4 c) {
  return __builtin_amdgcn_mfma_f32_16x16x32_bf16(
      __builtin_bit_cast(bf16x8, a), __builtin_bit_cast(bf16x8, b), c, 0, 0, 0);
}

// ---------------- weight prep ----------------
// wd image:   [8 chunks][128 o][40 (32 valid + 8 pad)] = 40960 elems
// wrs2 image: [3 passes][4 kk][128 o][32 k] unpadded   = 49152 elems
__global__ void wn_prep(const float* __restrict__ wd, const float* __restrict__ wres,
                        const float* __restrict__ wskip, unsigned short* __restrict__ ws16) {
  int g = blockIdx.x * 256 + threadIdx.x;   // grid 352*256 = 90112 exactly
  if (g < 40960) {
    int kc = g / 5120, rem = g - kc * 5120;
    int o = rem / 40, c = rem - o * 40;
    float v = 0.f;
    if (c < 32) {
      int k = kc * 32 + c;
      int tap = k >> 7, i = k & 127;
      v = wd[(o << 8) + (i << 1) + tap];   // w_dil[o][i][tap], shape (128,128,2)
    }
    ws16[g] = f2bf(v);
  } else {
    int g2 = g - 40960;  // < 49152
    int pkk = g2 >> 12;           // 0..11
    int rem = g2 & 4095;
    int o = rem >> 5, kl = rem & 31;
    int p = pkk >> 2, kk = pkk & 3;
    int k = kk * 32 + kl;
    float v = (p == 0) ? wres[o * 128 + k] : wskip[((p - 1) * 128 + o) * 128 + k];
    ws16[40960 + g2] = f2bf(v);
  }
}

// ---------------- fused main kernel ----------------
// 256 threads (4 waves, 2Mx2N), T-tile 64. LDS shorts:
//   region1 @0: xls[2][64][40] (2x2560) aliased by actT[64][136] (8704)
//   wls     @8704: 2 x [128][40] (2x5120) — stage-1 wd chunks AND stage-2 wrs chunks
// total 18944 sh = 37888 B -> 4 blocks/CU; __launch_bounds__(256,4) -> 16 waves/CU.
__global__ __launch_bounds__(256, 4) void wn_main(
    const float* __restrict__ x,
    const float* __restrict__ bres_g,
    const float* __restrict__ bskip_g,
    const unsigned short* __restrict__ wd_img,
    const unsigned short* __restrict__ wrs2_img,
    float* __restrict__ out,
    float* __restrict__ skipo) {
  extern __shared__ unsigned short lds[];
  unsigned short* xls  = lds;          // [2][64][40]
  unsigned short* actT = lds;          // [64][136], aliases xls (sequenced)
  unsigned short* wls  = lds + 8704;   // [2][128][40]

  // XCD swizzle: consecutive workgroups round-robin XCDs; give XCD c batch c,
  // tiles in order -> tap0/tap1 L2 reuse + L2-resident weight image per XCD.
  const int w = blockIdx.x;            // 0..1983
  const int b = w & 7;
  const int tile = w >> 3;             // 0..247
  const int t0 = tile * 64;

  const int tid = threadIdx.x;
  const int lane = tid & 63;
  const int wv = tid >> 6;
  const int mw = wv >> 1;     // 0..1 -> M offset mw*64
  const int nw = wv & 1;      // 0..1 -> N offset nw*32
  const int l15 = lane & 15;
  const int lhi = lane >> 4;

  // staging mapping: k-major lanes
  const int kq = tid & 7;     // k-group of 4
  const int tpr = tid >> 3;   // 0..31 -> t pair

  const float* xb_base = x + (size_t)b * (128 * 16384);

  float2 xr[4];
  uint4 wrA, wrB, wrC;

  auto issueX = [&](int kc) {
    int kglob = kc * 32 + kq * 4;
    int tap = kglob >> 7;
    int ib = kglob & 127;
    const float* p = xb_base + (size_t)ib * 16384 + (t0 + tap * 512 + tpr * 2);
    xr[0] = *(const float2*)(p);
    xr[1] = *(const float2*)(p + 16384);
    xr[2] = *(const float2*)(p + 32768);
    xr[3] = *(const float2*)(p + 49152);
  };
  auto writeX = [&](int buf) {
    unsigned short* dst = xls + buf * 2560;
    int r0 = tpr * 2;
    ushort4 a0, a1;
    a0.x = f2bf(xr[0].x); a0.y = f2bf(xr[1].x); a0.z = f2bf(xr[2].x); a0.w = f2bf(xr[3].x);
    a1.x = f2bf(xr[0].y); a1.y = f2bf(xr[1].y); a1.z = f2bf(xr[2].y); a1.w = f2bf(xr[3].y);
    *(ushort4*)(dst + r0 * 40 + kq * 4) = a0;
    *(ushort4*)(dst + (r0 + 1) * 40 + kq * 4) = a1;
  };
  auto loadW1 = [&](int kc) {   // wd chunk: 5120 sh = 640 uint4, 256 threads
    const uint4* src = (const uint4*)(wd_img + kc * 5120);
    wrA = src[tid];
    wrB = src[tid + 256];
    if (tid < 128) wrC = src[tid + 512];
  };
  auto writeW1 = [&](int buf) {
    uint4* dst = (uint4*)(wls + buf * 5120);
    dst[tid] = wrA;
    dst[tid + 256] = wrB;
    if (tid < 128) dst[tid + 512] = wrC;
  };
  auto loadW2 = [&](int p, int kk) {  // wrs2 chunk [128][32] = 512 uint4
    const uint4* src = (const uint4*)(wrs2_img + ((p * 4 + kk) << 12));
    wrA = src[tid];
    wrB = src[tid + 256];
  };
  auto writeW2 = [&](int buf) {       // insert pad-40 at write time
    unsigned short* base = wls + buf * 5120;
    int u0 = tid, u1 = tid + 256;     // uint4 index = 8 shorts
    *(uint4*)(base + (u0 >> 2) * 40 + (u0 & 3) * 8) = wrA;
    *(uint4*)(base + (u1 >> 2) * 40 + (u1 & 3) * 8) = wrB;
  };

  f32x4 acc[4][2];
#pragma unroll
  for (int i = 0; i < 4; ++i)
#pragma unroll
    for (int j = 0; j < 2; ++j) acc[i][j] = (f32x4){0.f, 0.f, 0.f, 0.f};

  // ---- stage 1: pre = [W0|W1] @ [x(t); x(t+512)], K=256 in 8 chunks ----
  issueX(0); loadW1(0);
  writeX(0); writeW1(0);
  __syncthreads();

#pragma unroll
  for (int kc = 0; kc < 8; ++kc) {
    const int buf = kc & 1;
    if (kc < 7) { issueX(kc + 1); loadW1(kc + 1); }
    const unsigned short* wbuf = wls + buf * 5120;
    const unsigned short* xbuf = xls + buf * 2560;
    uint4 af[4], bfr[2];
#pragma unroll
    for (int mi = 0; mi < 4; ++mi)
      af[mi] = *(const uint4*)(wbuf + (mw * 64 + mi * 16 + l15) * 40 + lhi * 8);
#pragma unroll
    for (int ni = 0; ni < 2; ++ni)
      bfr[ni] = *(const uint4*)(xbuf + (nw * 32 + ni * 16 + l15) * 40 + lhi * 8);
#pragma unroll
    for (int mi = 0; mi < 4; ++mi)
#pragma unroll
      for (int ni = 0; ni < 2; ++ni)
        acc[mi][ni] = MFMA16(af[mi], bfr[ni], acc[mi][ni]);
    if (kc < 7) { writeX(buf ^ 1); writeW1(buf ^ 1); }
    __syncthreads();
  }

  // ---- activation -> actT[t][o] (aliases xls; ordered by last sync) ----
#pragma unroll
  for (int mi = 0; mi < 4; ++mi) {
#pragma unroll
    for (int ni = 0; ni < 2; ++ni) {
      ushort4 av;
#pragma unroll
      for (int r = 0; r < 4; ++r) {
        float p = acc[mi][ni][r];
        p = fminf(fmaxf(p, -15.f), 15.f);
        float ep = __expf(p);
        float e2 = ep * ep;
        float sg = ep * __builtin_amdgcn_rcpf(1.f + ep);
        float th = (e2 - 1.f) * __builtin_amdgcn_rcpf(e2 + 1.f);
        ((unsigned short*)&av)[r] = f2bf(th * sg);
      }
      int trow = nw * 32 + ni * 16 + l15;
      int o0 = mw * 64 + mi * 16 + lhi * 4;
      *(ushort4*)(actT + trow * 136 + o0) = av;
    }
  }

  // ---- stage 2: out (pass 0) and skip (passes 1,2); K=128 in 4 chunks,
  //      weights double-buffered through wls ----
  const int npass = (tile >= 184) ? 3 : 1;
  for (int p = 0; p < npass; ++p) {
    loadW2(p, 0);
    writeW2(0);
    __syncthreads();   // also orders actT writes (p==0) / wls reuse (p>0)

    f32x4 acc2[4][2];
#pragma unroll
    for (int i = 0; i < 4; ++i)
#pragma unroll
      for (int j = 0; j < 2; ++j) acc2[i][j] = (f32x4){0.f, 0.f, 0.f, 0.f};

#pragma unroll
    for (int kk = 0; kk < 4; ++kk) {
      const int buf = kk & 1;
      if (kk < 3) loadW2(p, kk + 1);
      const unsigned short* wbuf = wls + buf * 5120;
      uint4 af[4], bfr[2];
#pragma unroll
      for (int mi = 0; mi < 4; ++mi)
        af[mi] = *(const uint4*)(wbuf + (mw * 64 + mi * 16 + l15) * 40 + lhi * 8);
#pragma unroll
      for (int ni = 0; ni < 2; ++ni)
        bfr[ni] = *(const uint4*)(actT + (nw * 32 + ni * 16 + l15) * 136 + kk * 32 + lhi * 8);
#pragma unroll
      for (int mi = 0; mi < 4; ++mi)
#pragma unroll
        for (int ni = 0; ni < 2; ++ni)
          acc2[mi][ni] = MFMA16(af[mi], bfr[ni], acc2[mi][ni]);
      if (kk < 3) writeW2(buf ^ 1);
      __syncthreads();
    }

    if (p == 0) {
#pragma unroll
      for (int mi = 0; mi < 4; ++mi) {
        int o0 = mw * 64 + mi * 16 + lhi * 4;
        float br[4];
#pragma unroll
        for (int r = 0; r < 4; ++r) br[r] = bres_g[o0 + r];
#pragma unroll
        for (int ni = 0; ni < 2; ++ni) {
          int tl = nw * 32 + ni * 16 + l15;
#pragma unroll
          for (int r = 0; r < 4; ++r) {
            size_t row = (size_t)(b * 128 + o0 + r);
            float v = acc2[mi][ni][r] + br[r] + x[row * 16384 + 512 + t0 + tl];
            out[row * 15872 + t0 + tl] = v;
          }
        }
      }
    } else {
#pragma unroll
      for (int mi = 0; mi < 4; ++mi) {
        int o2 = (p - 1) * 128 + mw * 64 + mi * 16 + lhi * 4;
        float bs[4];
#pragma unroll
        for (int r = 0; r < 4; ++r) bs[r] = bskip_g[o2 + r];
#pragma unroll
        for (int ni = 0; ni < 2; ++ni) {
          int tl = nw * 32 + ni * 16 + l15;
          int s = t0 + tl - 11776;
#pragma unroll
          for (int r = 0; r < 4; ++r) {
            skipo[(size_t)(b * 256 + o2 + r) * 4096 + s] = acc2[mi][ni][r] + bs[r];
          }
        }
      }
    }
  }
}

extern "C" void kernel_launch(void* const* d_in, const int* in_sizes, int n_in,
                              void* d_out, int out_size, void* d_ws, size_t ws_size,
                              hipStream_t stream) {
  const float* x      = (const float*)d_in[0];
  const float* w_dil  = (const float*)d_in[1];
  const float* w_res  = (const float*)d_in[2];
  const float* b_res  = (const float*)d_in[3];
  const float* w_skip = (const float*)d_in[4];
  const float* b_skip = (const float*)d_in[5];
  unsigned short* ws16 = (unsigned short*)d_ws;
  float* out = (float*)d_out;
  float* skipo = out + 16252928;  // 8*128*15872

  wn_prep<<<352, 256, 0, stream>>>(w_dil, w_res, w_skip, ws16);

  wn_main<<<1984, 256, 37888, stream>>>(x, b_res, b_skip, ws16, ws16 + 40960, out, skipo);
}